// Round 3
// baseline (9.673 us; speedup 1.0000x reference)
//
#include <hip/hip_runtime.h>
#include <cstddef>

#define BB   16
#define LL   4096
#define DD   512
#define OUTN 512
#define OCHUNK 32   // outputs per block (grid.y = OUTN/OCHUNK = 16)

__global__ __launch_bounds__(256) void fluct_kernel(
    const float* __restrict__ X,            // (B, L, D)
    const int*   __restrict__ mask,         // (B, L)
    const float* __restrict__ alpha_logits, // (2,)
    const float* __restrict__ W,            // (OUT, D)
    const float* __restrict__ bias,         // (OUT,)
    float*       __restrict__ out)          // (B, OUT)
{
    const int b    = blockIdx.x;
    const int tid  = threadIdx.x;
    const int lane = tid & 63;

    const int o_local = tid >> 3;   // 0..31
    const int sub     = tid & 7;    // 0..7  (8 threads per output)
    const int o       = blockIdx.y * OCHUNK + o_local;

    __shared__ float z_s[DD];

    // ---- Phase 0: all len-independent loads issued up front ----
    const float4* Wrow = (const float4*)(W + (size_t)o * DD);  // 128 float4/row
    float4 w[16];
    #pragma unroll
    for (int i = 0; i < 16; ++i) w[i] = Wrow[i * 8 + sub];
    const float bias_o = bias[o];
    const float l0 = alpha_logits[0], l1 = alpha_logits[1];

    const float* Xb = X + (size_t)b * LL * DD;
    // S[0]=X[b,1], S[1]=X[b,2] never depend on len -> prefetch now.
    const float s0a = Xb[DD + tid];
    const float s1a = Xb[2 * DD + tid];
    const float s0b = Xb[DD + tid + 256];
    const float s1b = Xb[2 * DD + tid + 256];

    // ---- Phase 1: len = sum(mask[b,1:]) — per-wave full-row scan ----
    // Each wave redundantly covers all 1024 int4 (16/lane, one round-trip),
    // making len wave-uniform via shfl tree alone: no LDS, no barrier on the
    // dependent chain.
    const int* mrow = mask + (size_t)b * LL;
    const int  m0   = mrow[0];            // exclude j=0 after the sum
    const int4* m4  = (const int4*)mrow;
    int local = 0;
    #pragma unroll
    for (int k = 0; k < 16; ++k) {
        const int4 v = m4[lane + 64 * k];
        local += v.x + v.y + v.z + v.w;
    }
    #pragma unroll
    for (int off = 1; off < 64; off <<= 1) local += __shfl_xor(local, off, 64);
    const int len = local - m0;

    // softmax(alpha_logits)
    const float mx = fmaxf(l0, l1);
    const float e0 = __expf(l0 - mx), e1 = __expf(l1 - mx);
    const float inv = 1.0f / (e0 + e1);
    const float a1 = e0 * inv, a2 = e1 * inv;

    // ---- Phase 2: z into LDS (telescoped) ----
    // len==0: z=0 ; len==1: z=S[0] ;
    // len>=2: z = (a1*(S[len-1]-S[0]) + a2*(S[len-1]+S[len-2]-S[0]-S[1]))/(len-1)
    {
        float zv0 = 0.0f, zv1 = 0.0f;
        if (len == 1) {
            zv0 = s0a; zv1 = s0b;
        } else if (len >= 2) {
            const float sl1a = Xb[(size_t)len * DD + tid];         // S[len-1]
            const float sl2a = Xb[(size_t)(len - 1) * DD + tid];   // S[len-2]
            const float sl1b = Xb[(size_t)len * DD + tid + 256];
            const float sl2b = Xb[(size_t)(len - 1) * DD + tid + 256];
            const float dinv = 1.0f / (float)(len - 1);
            zv0 = (a1 * (sl1a - s0a) + a2 * (sl1a + sl2a - s0a - s1a)) * dinv;
            zv1 = (a1 * (sl1b - s0b) + a2 * (sl1b + sl2b - s0b - s1b)) * dinv;
        }
        z_s[tid]       = zv0;
        z_s[tid + 256] = zv1;
    }
    __syncthreads();

    // ---- Phase 3: out[b,o] = z . W[o,:] + bias[o] ----
    // z4 reads are uniform per 8-lane group -> LDS broadcast, conflict-free.
    const float4* z4 = (const float4*)z_s;
    float acc = 0.0f;
    #pragma unroll
    for (int i = 0; i < 16; ++i) {
        const float4 zv = z4[i * 8 + sub];
        acc += w[i].x * zv.x + w[i].y * zv.y + w[i].z * zv.z + w[i].w * zv.w;
    }
    acc += __shfl_xor(acc, 1, 64);
    acc += __shfl_xor(acc, 2, 64);
    acc += __shfl_xor(acc, 4, 64);
    if (sub == 0) out[(size_t)b * OUTN + o] = acc + bias_o;
}

extern "C" void kernel_launch(void* const* d_in, const int* in_sizes, int n_in,
                              void* d_out, int out_size, void* d_ws, size_t ws_size,
                              hipStream_t stream) {
    const float* X            = (const float*)d_in[0];
    const int*   attn_mask    = (const int*)d_in[1];
    const float* alpha_logits = (const float*)d_in[2];
    const float* W            = (const float*)d_in[3];
    const float* bias         = (const float*)d_in[4];
    float* out = (float*)d_out;

    dim3 grid(BB, OUTN / OCHUNK);
    fluct_kernel<<<grid, 256, 0, stream>>>(X, attn_mask, alpha_logits, W, bias, out);
}